// Round 16
// baseline (96.918 us; speedup 1.0000x reference)
//
#include <hip/hip_runtime.h>
#include <hip/hip_bf16.h>

#define N_NODES 50000
#define N_EDGES 640000
#define C 128            // IN_C == HID
#define NB 196           // dst buckets of 256 nodes (50000 <= 196*256)
#define BCAP 5120        // per-bucket slot (raw mean 3277, pad4 mean ~3780, +12 sigma)
#define NTILES (N_NODES / 16)                               // 3125
#define PART_EPB 2048    // edges per partition block
#define PART_BLOCKS ((N_EDGES + PART_EPB - 1) / PART_EPB)   // 313

typedef __bf16 bf16x8 __attribute__((ext_vector_type(8)));
typedef __bf16 bf16x4 __attribute__((ext_vector_type(4)));
typedef float  f32x4  __attribute__((ext_vector_type(4)));
typedef float  f32x2  __attribute__((ext_vector_type(2)));
typedef unsigned int u32x4 __attribute__((ext_vector_type(4)));

// ---- d_ws layout (byte offsets) ----
#define WS_GCUR   0          // NB ints (bucket cursors; zeroed by precomp blk0)
#define WS_OFFS   1024       // N ints (padded range start)
#define WS_OFFE   201216     // N ints (padded range end)
#define WS_SRCD   401408     // NB*BCAP int2 + 128B slack (src id, dist bits)
#define WS_REC    8429824    // NB*BCAP u32 packed records (src | dstLocal<<16)
#define WS_HDST   12443904   // N*C bf16 (Hdst + bias)
#define WS_HSRC8  25243904   // (N+1)*C fp8 e4m3 (row N = dummy, all 0xFE)
#define WS_EMBB   31644160   // N*C bf16 (embed, pre-converted)
#define WS_AGGR   44444160   // N*C bf16 (aggregation result)
// total ~57.2 MB

// XOR-swizzle for [16][128]-short LDS tiles (2-way residual conflict = free).
__device__ __forceinline__ int swzS(int row, int soff) {
    return row * 128 + (soff ^ ((row & 7) << 3));
}
// [16][256]-short variant (node-update staging)
__device__ __forceinline__ int swz8(int row, int soff) {
    return row * 256 + (soff ^ ((row & 7) << 3));
}

// ---------------------------------------------------------------------------
// Precompute Hsrc = embed @ Wmsg[0:128]          (fp8 e4m3, ws)
//            Hdst = embed @ Wmsg[128:256] + b    (bf16, ws)
//            embedB = bf16(embed)                (free: staging regs re-stored)
// Grid 625 -> exactly 5 tiles/block. Block 0 zeroes gcur + writes dummy row.
// ---------------------------------------------------------------------------
__global__ __launch_bounds__(512) void precomp_kernel(
    const float* __restrict__ embed, const float* __restrict__ Wmsg,
    const float* __restrict__ bmsg,  unsigned char* __restrict__ Hsrc8,
    __bf16* __restrict__ Hdst, __bf16* __restrict__ embedB,
    int* __restrict__ gcur)
{
    __shared__ short lds[16 * 128];

    const int t = threadIdx.x, lane = t & 63, wave = t >> 6;
    const int chbase = wave * 16, q = lane >> 4, nr = lane & 15;
    const int ch = chbase + nr;

    if (blockIdx.x == 0) {
        if (t < NB) gcur[t] = 0;
        if (t < 16)  // dummy row: relu(-448 + hd + 0) == 0 for any real hd
            *(unsigned long long*)(Hsrc8 + (long)N_NODES * C + t * 8) =
                0xFEFEFEFEFEFEFEFEULL;
    }

    bf16x8 aS[4], aD[4];
    #pragma unroll
    for (int ks = 0; ks < 4; ++ks)
        #pragma unroll
        for (int i = 0; i < 8; ++i) {
            const int k = ks * 32 + q * 8 + i;
            aS[ks][i] = (__bf16)Wmsg[k * C + ch];
            aD[ks][i] = (__bf16)Wmsg[(128 + k) * C + ch];
        }
    float bias[4];
    #pragma unroll
    for (int r = 0; r < 4; ++r) bias[r] = bmsg[chbase + q * 4 + r];

    for (int nt = blockIdx.x; nt < NTILES; nt += gridDim.x) {
        const int n0 = nt * 16;
        {   // stage 16 nodes x 128 feats: f32 -> bf16 LDS (+ store embedB copy)
            const int row = t >> 5, seg = t & 31;
            const float4 f = *(const float4*)(embed + (long)(n0 + row) * C + seg * 4);
            bf16x4 v;
            v[0]=(__bf16)f.x; v[1]=(__bf16)f.y; v[2]=(__bf16)f.z; v[3]=(__bf16)f.w;
            *(bf16x4*)(&lds[swzS(row, seg * 4)]) = v;
            *(bf16x4*)(embedB + (long)(n0 + row) * C + seg * 4) = v;
        }
        __syncthreads();

        f32x4 hs = {0.f,0.f,0.f,0.f}, hd = {0.f,0.f,0.f,0.f};
        #pragma unroll
        for (int ks = 0; ks < 4; ++ks) {
            const bf16x8 b = *(const bf16x8*)(&lds[swzS(nr, ks * 32 + q * 8)]);
            hs = __builtin_amdgcn_mfma_f32_16x16x32_bf16(aS[ks], b, hs, 0, 0, 0);
            hd = __builtin_amdgcn_mfma_f32_16x16x32_bf16(aD[ks], b, hd, 0, 0, 0);
        }
        __syncthreads();

        const int node = n0 + nr;            // D: col=node, row(q*4+r)=ch
        int w8 = 0;
        w8 = __builtin_amdgcn_cvt_pk_fp8_f32(hs[0], hs[1], w8, false);
        w8 = __builtin_amdgcn_cvt_pk_fp8_f32(hs[2], hs[3], w8, true);
        *(unsigned*)(Hsrc8 + (long)node * C + chbase + q * 4) = (unsigned)w8;
        bf16x4 vd;
        #pragma unroll
        for (int r = 0; r < 4; ++r) vd[r] = (__bf16)(hd[r] + bias[r]);
        *(bf16x4*)(Hdst + (long)node * C + chbase + q * 4) = vd;
    }
}

// ---------------------------------------------------------------------------
// partition: bin 2048 edges/block (8/thread) by dst>>8 via LDS counters;
// reserve a range in the bucket's FIXED slot with ONE global atomic per
// bucket per block (313 blocks -> half the per-address atomic chain depth);
// write packed 4B records (src | dstLocal<<16).
// ---------------------------------------------------------------------------
__global__ __launch_bounds__(256) void partition_kernel(
    const int* __restrict__ eidx, int* __restrict__ gcur,
    unsigned* __restrict__ rec)
{
    __shared__ int cnt[NB];
    __shared__ int base[NB];
    const int t = threadIdx.x;
    if (t < NB) cnt[t] = 0;
    __syncthreads();
    const int e0 = blockIdx.x * PART_EPB;
    int lrank[8], bb[8];
    unsigned prec[8];
    #pragma unroll
    for (int k = 0; k < 8; ++k) {
        const int e = e0 + k * 256 + t;
        bb[k] = -1;
        if (e < N_EDGES) {
            const int r = eidx[e], c = eidx[N_EDGES + e];
            bb[k]   = c >> 8;
            prec[k] = (unsigned)r | ((unsigned)(c & 255) << 16);
            lrank[k] = atomicAdd(&cnt[bb[k]], 1);
        }
    }
    __syncthreads();
    if (t < NB) base[t] = t * BCAP + atomicAdd(&gcur[t], cnt[t]);
    __syncthreads();
    #pragma unroll
    for (int k = 0; k < 8; ++k)
        if (bb[k] >= 0) rec[base[bb[k]] + lrank[k]] = prec[k];
}

// ---------------------------------------------------------------------------
// bucket_csr: one block per bucket. LDS deg-count -> scan of PADDED degrees
// (multiple of 4) -> offS/offE; scatter (src, dist) pairs; fill each node's
// tail [offS+deg, offS+pdeg) with dummy records (src=N_NODES, d=0).
// ---------------------------------------------------------------------------
__global__ __launch_bounds__(256) void bucket_csr_kernel(
    const unsigned* __restrict__ rec, const int* __restrict__ gcur,
    const float* __restrict__ pos, int* __restrict__ offS,
    int* __restrict__ offE, int2* __restrict__ srcD)
{
    __shared__ int   deg[256];
    __shared__ int   cur[256];
    __shared__ int   lds[256];
    __shared__ float dpx[256], dpy[256], dpz[256];
    const int t = threadIdx.x, b = blockIdx.x;
    const int r0 = b * BCAP, r1 = r0 + gcur[b], n0 = b << 8;
    deg[t] = 0;
    {   // stage this bucket's 256 dst positions
        const int nn = n0 + t;
        const int cl = min(nn, N_NODES - 1);
        dpx[t] = pos[cl * 3]; dpy[t] = pos[cl * 3 + 1]; dpz[t] = pos[cl * 3 + 2];
    }
    __syncthreads();
    for (int i = r0 + t; i < r1; i += 256)
        atomicAdd(&deg[rec[i] >> 16], 1);
    __syncthreads();
    const int v  = deg[t];
    const int pd = (v + 3) & ~3;          // pad to multiple of 4
    lds[t] = pd;
    __syncthreads();
    for (int s = 1; s < 256; s <<= 1) {
        const int u = (t >= s) ? lds[t - s] : 0;
        __syncthreads();
        lds[t] += u;
        __syncthreads();
    }
    const int excl = r0 + lds[t] - pd;
    cur[t] = excl;
    if (n0 + t < N_NODES) { offS[n0 + t] = excl; offE[n0 + t] = excl + pd; }
    // dummy tail (disjoint from scatter range; no extra sync needed)
    for (int i = excl + v; i < excl + pd; ++i)
        srcD[i] = make_int2(N_NODES, 0);
    __syncthreads();
    for (int i = r0 + t; i < r1; i += 256) {
        const unsigned rc = rec[i];
        const int dl  = (int)(rc >> 16);
        const int src = (int)(rc & 0xFFFFu);
        const float dx = pos[src * 3]     - dpx[dl];
        const float dy = pos[src * 3 + 1] - dpy[dl];
        const float dz = pos[src * 3 + 2] - dpz[dl];
        const float d  = dx * dx + dy * dy + dz * dz;
        const int p = atomicAdd(&cur[dl], 1);
        srcD[p] = make_int2(src, __float_as_int(d));
    }
}

// ---------------------------------------------------------------------------
// Aggregate: ONE NODE PER WAVE, 4 groups x 16 lanes (8 ch/lane), 2-stage
// pipeline with 8 edges in flight. Lists padded to x4; the second 4-edge
// half of the last iteration is guarded by a WAVE-UNIFORM branch (e+4<o1).
// All gather indices clamped to the inert dummy row.
// ---------------------------------------------------------------------------
__global__ __launch_bounds__(256) void aggr_kernel(
    const unsigned char* __restrict__ Hsrc8, const __bf16* __restrict__ Hdst,
    const float*  __restrict__ Wmsg,
    const int*    __restrict__ offS, const int*   __restrict__ offE,
    const int2*   __restrict__ srcD, __bf16* __restrict__ aggrB)
{
    const int lane = threadIdx.x & 63;
    const int wv   = threadIdx.x >> 6;
    const int g    = lane >> 4;          // edge sub-group 0..3
    const int c8   = (lane & 15) * 8;    // channel base (8 ch/lane)

    float w2[8], hd[8], acc[8];
    *(f32x4*)&w2[0] = *(const f32x4*)(Wmsg + 256 * C + c8);
    *(f32x4*)&w2[4] = *(const f32x4*)(Wmsg + 256 * C + c8 + 4);

    const int n = blockIdx.x * 4 + wv;   // 12500*4 == 50000 exactly
    const int o0 = offS[n], o1 = offE[n];
    {   // unpack Hdst row slice (bf16 -> f32)
        const u32x4 hdb = *(const u32x4*)(Hdst + (long)n * C + c8);
        #pragma unroll
        for (int k = 0; k < 4; ++k) {
            hd[2*k]   = __uint_as_float(hdb[k] << 16);
            hd[2*k+1] = __uint_as_float(hdb[k] & 0xffff0000u);
        }
    }
    #pragma unroll
    for (int j = 0; j < 8; ++j) acc[j] = 0.f;

    if (o1 > o0) {
        // pipeline fill (all gathers clamped: tail/slack reads may be garbage)
        int2 sdA0 = srcD[o0 + g];
        int2 sdA1 = srcD[o0 + 4 + g];
        uint2 huA0 = *(const uint2*)(Hsrc8 +
            (long)min((unsigned)sdA0.x, (unsigned)N_NODES) * C + c8);
        uint2 huA1 = *(const uint2*)(Hsrc8 +
            (long)min((unsigned)sdA1.x, (unsigned)N_NODES) * C + c8);
        int2 sdB0 = srcD[o0 + 8 + g];
        int2 sdB1 = srcD[o0 + 12 + g];
        for (int e = o0; e < o1; e += 8) {
            // issue NEXT iteration's gathers (clamped)
            const long bx0 = (long)min((unsigned)sdB0.x, (unsigned)N_NODES);
            const long bx1 = (long)min((unsigned)sdB1.x, (unsigned)N_NODES);
            const uint2 huB0 = *(const uint2*)(Hsrc8 + bx0 * C + c8);
            const uint2 huB1 = *(const uint2*)(Hsrc8 + bx1 * C + c8);
            // load iter+2 ids (srcD has 128B slack past the last region)
            const int2 sdC0 = srcD[e + 16 + g];
            const int2 sdC1 = srcD[e + 20 + g];
            const float d0 = __int_as_float(sdA0.y);
            const float d1 = __int_as_float(sdA1.y);

            {   // consume half 0: edge e+g (always valid: o1-e >= 4)
                const f32x2 p0 = __builtin_amdgcn_cvt_pk_f32_fp8((int)huA0.x, false);
                const f32x2 p1 = __builtin_amdgcn_cvt_pk_f32_fp8((int)huA0.x, true);
                const f32x2 p2 = __builtin_amdgcn_cvt_pk_f32_fp8((int)huA0.y, false);
                const f32x2 p3 = __builtin_amdgcn_cvt_pk_f32_fp8((int)huA0.y, true);
                const float hs[8] = {p0[0],p0[1],p1[0],p1[1],p2[0],p2[1],p3[0],p3[1]};
                #pragma unroll
                for (int j = 0; j < 8; ++j)
                    acc[j] += fmaxf(hs[j] + fmaf(d0, w2[j], hd[j]), 0.f);
            }
            if (e + 4 < o1) {   // consume half 1 (wave-uniform guard)
                const f32x2 p0 = __builtin_amdgcn_cvt_pk_f32_fp8((int)huA1.x, false);
                const f32x2 p1 = __builtin_amdgcn_cvt_pk_f32_fp8((int)huA1.x, true);
                const f32x2 p2 = __builtin_amdgcn_cvt_pk_f32_fp8((int)huA1.y, false);
                const f32x2 p3 = __builtin_amdgcn_cvt_pk_f32_fp8((int)huA1.y, true);
                const float hs[8] = {p0[0],p0[1],p1[0],p1[1],p2[0],p2[1],p3[0],p3[1]};
                #pragma unroll
                for (int j = 0; j < 8; ++j)
                    acc[j] += fmaxf(hs[j] + fmaf(d1, w2[j], hd[j]), 0.f);
            }
            // shift pipeline
            sdA0 = sdB0; sdA1 = sdB1; sdB0 = sdC0; sdB1 = sdC1;
            huA0 = huB0; huA1 = huB1;
        }
    }
    #pragma unroll
    for (int j = 0; j < 8; ++j) {        // combine the 4 edge groups
        acc[j] += __shfl_xor(acc[j], 16);
        acc[j] += __shfl_xor(acc[j], 32);
    }
    if (lane < 16) {
        bf16x8 v;
        #pragma unroll
        for (int j = 0; j < 8; ++j) v[j] = (__bf16)acc[j];
        *(bf16x8*)(aggrB + (long)n * C + c8) = v;
    }
}

// ---------------------------------------------------------------------------
// Node update: out = embed @ W_res + relu([embed, aggr] @ W_upd + b_upd)
// Reads pre-converted embedB (bf16) + aggrB (bf16). Grid 625 -> exactly
// 5 tiles/block (balanced; amortizes the 96-value weight fragment load).
// ---------------------------------------------------------------------------
__global__ __launch_bounds__(512) void node_upd_kernel(
    const __bf16* __restrict__ embedB, const __bf16* __restrict__ aggrB,
    const float* __restrict__ Wres,  const float* __restrict__ Wupd,
    const float* __restrict__ bupd,  float* __restrict__ out)
{
    __shared__ short ldsF[16 * 256];

    const int t = threadIdx.x, lane = t & 63, wave = t >> 6;
    const int chbase = wave * 16, q = lane >> 4, nr = lane & 15;

    bf16x8 aU[8], aR[4];
    {
        const int ch = chbase + nr;
        #pragma unroll
        for (int ks = 0; ks < 8; ++ks)
            #pragma unroll
            for (int i = 0; i < 8; ++i)
                aU[ks][i] = (__bf16)Wupd[(ks*32 + q*8 + i) * C + ch];
        #pragma unroll
        for (int ks = 0; ks < 4; ++ks)
            #pragma unroll
            for (int i = 0; i < 8; ++i)
                aR[ks][i] = (__bf16)Wres[(ks*32 + q*8 + i) * C + ch];
    }
    float bu[4];
    #pragma unroll
    for (int r = 0; r < 4; ++r) bu[r] = bupd[chbase + q*4 + r];

    for (int nt = blockIdx.x; nt < NTILES; nt += gridDim.x) {
        const int n0 = nt * 16;
        {   // stage [embedB | aggrB] (both bf16 copies) for 16 nodes
            const int nn = t >> 5, seg = t & 31;
            const __bf16* base = (seg < 16) ? embedB : aggrB;
            const bf16x8 v = *(const bf16x8*)(base + (long)(n0 + nn) * C + (seg & 15) * 8);
            *(bf16x8*)(&ldsF[swz8(nn, seg * 8)]) = v;
        }
        __syncthreads();

        f32x4 au = {0.f,0.f,0.f,0.f}, ar = {0.f,0.f,0.f,0.f};
        #pragma unroll
        for (int ks = 0; ks < 8; ++ks) {
            const bf16x8 b = *(const bf16x8*)(&ldsF[swz8(nr, ks * 32 + q * 8)]);
            au = __builtin_amdgcn_mfma_f32_16x16x32_bf16(aU[ks], b, au, 0, 0, 0);
        }
        #pragma unroll
        for (int ks = 0; ks < 4; ++ks) {
            const bf16x8 b = *(const bf16x8*)(&ldsF[swz8(nr, ks * 32 + q * 8)]);
            ar = __builtin_amdgcn_mfma_f32_16x16x32_bf16(aR[ks], b, ar, 0, 0, 0);
        }
        __syncthreads();

        const int node = n0 + nr;
        float* dst = out + (long)node * C + chbase + q * 4;
        #pragma unroll
        for (int r = 0; r < 4; ++r)
            dst[r] = ar[r] + fmaxf(au[r] + bu[r], 0.f);
    }
}

extern "C" void kernel_launch(void* const* d_in, const int* in_sizes, int n_in,
                              void* d_out, int out_size, void* d_ws, size_t ws_size,
                              hipStream_t stream) {
    const float* embed = (const float*)d_in[0];
    const float* pos   = (const float*)d_in[1];
    const float* Wres  = (const float*)d_in[2];
    const float* Wmsg  = (const float*)d_in[3];
    const float* bmsg  = (const float*)d_in[4];
    const float* Wupd  = (const float*)d_in[5];
    const float* bupd  = (const float*)d_in[6];
    const int*   eidx  = (const int*)d_in[7];
    float* out = (float*)d_out;

    char* ws = (char*)d_ws;
    int*            gcur  = (int*)(ws + WS_GCUR);
    int*            offS  = (int*)(ws + WS_OFFS);
    int*            offE  = (int*)(ws + WS_OFFE);
    int2*           srcD  = (int2*)(ws + WS_SRCD);
    unsigned*       rec   = (unsigned*)(ws + WS_REC);
    __bf16*         HdstB = (__bf16*)(ws + WS_HDST);
    unsigned char*  Hsrc8 = (unsigned char*)(ws + WS_HSRC8);
    __bf16*         embB  = (__bf16*)(ws + WS_EMBB);
    __bf16*         aggrB = (__bf16*)(ws + WS_AGGR);

    precomp_kernel<<<625, 512, 0, stream>>>(embed, Wmsg, bmsg, Hsrc8, HdstB, embB, gcur);
    partition_kernel<<<PART_BLOCKS, 256, 0, stream>>>(eidx, gcur, rec);
    bucket_csr_kernel<<<NB, 256, 0, stream>>>(rec, gcur, pos, offS, offE, srcD);
    aggr_kernel<<<N_NODES / 4, 256, 0, stream>>>(Hsrc8, HdstB, Wmsg, offS, offE, srcD, aggrB);
    node_upd_kernel<<<625, 512, 0, stream>>>(embB, aggrB, Wres, Wupd, bupd, out);
}

// Round 17
// 94.874 us; speedup vs baseline: 1.0215x; 1.0215x over previous
//
#include <hip/hip_runtime.h>
#include <hip/hip_bf16.h>

#define N_NODES 50000
#define N_EDGES 640000
#define C 128            // IN_C == HID
#define NB 196           // dst buckets of 256 nodes (50000 <= 196*256)
#define BCAP 5120        // per-bucket slot (raw mean 3277, padded mean 4199, +15 sigma)
#define NTILES (N_NODES / 16)                               // 3125

typedef __bf16 bf16x8 __attribute__((ext_vector_type(8)));
typedef __bf16 bf16x4 __attribute__((ext_vector_type(4)));
typedef float  f32x4  __attribute__((ext_vector_type(4)));
typedef float  f32x2  __attribute__((ext_vector_type(2)));
typedef unsigned int u32x4 __attribute__((ext_vector_type(4)));

// ---- d_ws layout (byte offsets) ----
#define WS_GCUR   0          // NB ints (bucket cursors; zeroed by precomp blk0)
#define WS_OFFS   1024       // N ints (padded range start)
#define WS_OFFE   201216     // N ints (padded range end)
#define WS_SRCD   401408     // NB*BCAP int2 + slack (src id, dist bits)
#define WS_REC    8429824    // NB*BCAP u32 packed records (src | dstLocal<<16)
#define WS_HDST   12443904   // N*C bf16 (Hdst + bias)
#define WS_HSRC8  25243904   // (N+1)*C fp8 e4m3 (row N = dummy, all 0xFE)
#define WS_EMBB   31644160   // N*C bf16 (embed, pre-converted)
#define WS_AGGR   44444160   // N*C bf16 (aggregation result)
// total ~57.2 MB

// XOR-swizzle for [16][128]-short LDS tiles (2-way residual conflict = free).
__device__ __forceinline__ int swzS(int row, int soff) {
    return row * 128 + (soff ^ ((row & 7) << 3));
}
// [16][256]-short variant (node-update staging)
__device__ __forceinline__ int swz8(int row, int soff) {
    return row * 256 + (soff ^ ((row & 7) << 3));
}

// ---------------------------------------------------------------------------
// Precompute Hsrc = embed @ Wmsg[0:128]          (fp8 e4m3, ws)
//            Hdst = embed @ Wmsg[128:256] + b    (bf16, ws)
//            embedB = bf16(embed)                (free: staging regs re-stored)
// Block 0 zeroes gcur and writes the dummy Hsrc8 row (0xFE = -448 fp8).
// ---------------------------------------------------------------------------
__global__ __launch_bounds__(512) void precomp_kernel(
    const float* __restrict__ embed, const float* __restrict__ Wmsg,
    const float* __restrict__ bmsg,  unsigned char* __restrict__ Hsrc8,
    __bf16* __restrict__ Hdst, __bf16* __restrict__ embedB,
    int* __restrict__ gcur)
{
    __shared__ short lds[16 * 128];

    const int t = threadIdx.x, lane = t & 63, wave = t >> 6;
    const int chbase = wave * 16, q = lane >> 4, nr = lane & 15;
    const int ch = chbase + nr;

    if (blockIdx.x == 0) {
        if (t < NB) gcur[t] = 0;
        if (t < 16)  // dummy row: relu(-448 + hd + 0) == 0 for any real hd
            *(unsigned long long*)(Hsrc8 + (long)N_NODES * C + t * 8) =
                0xFEFEFEFEFEFEFEFEULL;
    }

    bf16x8 aS[4], aD[4];
    #pragma unroll
    for (int ks = 0; ks < 4; ++ks)
        #pragma unroll
        for (int i = 0; i < 8; ++i) {
            const int k = ks * 32 + q * 8 + i;
            aS[ks][i] = (__bf16)Wmsg[k * C + ch];
            aD[ks][i] = (__bf16)Wmsg[(128 + k) * C + ch];
        }
    float bias[4];
    #pragma unroll
    for (int r = 0; r < 4; ++r) bias[r] = bmsg[chbase + q * 4 + r];

    for (int nt = blockIdx.x; nt < NTILES; nt += gridDim.x) {
        const int n0 = nt * 16;
        {   // stage 16 nodes x 128 feats: f32 -> bf16 LDS (+ store embedB copy)
            const int row = t >> 5, seg = t & 31;
            const float4 f = *(const float4*)(embed + (long)(n0 + row) * C + seg * 4);
            bf16x4 v;
            v[0]=(__bf16)f.x; v[1]=(__bf16)f.y; v[2]=(__bf16)f.z; v[3]=(__bf16)f.w;
            *(bf16x4*)(&lds[swzS(row, seg * 4)]) = v;
            *(bf16x4*)(embedB + (long)(n0 + row) * C + seg * 4) = v;
        }
        __syncthreads();

        f32x4 hs = {0.f,0.f,0.f,0.f}, hd = {0.f,0.f,0.f,0.f};
        #pragma unroll
        for (int ks = 0; ks < 4; ++ks) {
            const bf16x8 b = *(const bf16x8*)(&lds[swzS(nr, ks * 32 + q * 8)]);
            hs = __builtin_amdgcn_mfma_f32_16x16x32_bf16(aS[ks], b, hs, 0, 0, 0);
            hd = __builtin_amdgcn_mfma_f32_16x16x32_bf16(aD[ks], b, hd, 0, 0, 0);
        }
        __syncthreads();

        const int node = n0 + nr;            // D: col=node, row(q*4+r)=ch
        int w8 = 0;
        w8 = __builtin_amdgcn_cvt_pk_fp8_f32(hs[0], hs[1], w8, false);
        w8 = __builtin_amdgcn_cvt_pk_fp8_f32(hs[2], hs[3], w8, true);
        *(unsigned*)(Hsrc8 + (long)node * C + chbase + q * 4) = (unsigned)w8;
        bf16x4 vd;
        #pragma unroll
        for (int r = 0; r < 4; ++r) vd[r] = (__bf16)(hd[r] + bias[r]);
        *(bf16x4*)(Hdst + (long)node * C + chbase + q * 4) = vd;
    }
}

// ---------------------------------------------------------------------------
// partition: bin 1024 edges/block by dst>>8 via LDS counters; reserve a range
// in the bucket's FIXED slot [b*BCAP, (b+1)*BCAP) with one global atomic per
// bucket per block; write packed 4B records (src | dstLocal<<16).
// ---------------------------------------------------------------------------
__global__ __launch_bounds__(256) void partition_kernel(
    const int* __restrict__ eidx, int* __restrict__ gcur,
    unsigned* __restrict__ rec)
{
    __shared__ int cnt[NB];
    __shared__ int base[NB];
    const int t = threadIdx.x;
    if (t < NB) cnt[t] = 0;
    __syncthreads();
    const int e0 = blockIdx.x * 1024;
    int lrank[4], bb[4];
    unsigned prec[4];
    #pragma unroll
    for (int k = 0; k < 4; ++k) {
        const int e = e0 + k * 256 + t;
        const int r = eidx[e], c = eidx[N_EDGES + e];
        bb[k]   = c >> 8;
        prec[k] = (unsigned)r | ((unsigned)(c & 255) << 16);
        lrank[k] = atomicAdd(&cnt[bb[k]], 1);
    }
    __syncthreads();
    if (t < NB) base[t] = t * BCAP + atomicAdd(&gcur[t], cnt[t]);
    __syncthreads();
    #pragma unroll
    for (int k = 0; k < 4; ++k)
        rec[base[bb[k]] + lrank[k]] = prec[k];
}

// ---------------------------------------------------------------------------
// bucket_csr: one block per bucket. LDS deg-count -> scan of PADDED degrees
// (multiple of 8) -> offS/offE; scatter (src, dist) pairs; fill each node's
// tail [offS+deg, offS+pdeg) with dummy records (src=N_NODES, d=0).
// ---------------------------------------------------------------------------
__global__ __launch_bounds__(256) void bucket_csr_kernel(
    const unsigned* __restrict__ rec, const int* __restrict__ gcur,
    const float* __restrict__ pos, int* __restrict__ offS,
    int* __restrict__ offE, int2* __restrict__ srcD)
{
    __shared__ int   deg[256];
    __shared__ int   cur[256];
    __shared__ int   lds[256];
    __shared__ float dpx[256], dpy[256], dpz[256];
    const int t = threadIdx.x, b = blockIdx.x;
    const int r0 = b * BCAP, r1 = r0 + gcur[b], n0 = b << 8;
    deg[t] = 0;
    {   // stage this bucket's 256 dst positions
        const int nn = n0 + t;
        const int cl = min(nn, N_NODES - 1);
        dpx[t] = pos[cl * 3]; dpy[t] = pos[cl * 3 + 1]; dpz[t] = pos[cl * 3 + 2];
    }
    __syncthreads();
    for (int i = r0 + t; i < r1; i += 256)
        atomicAdd(&deg[rec[i] >> 16], 1);
    __syncthreads();
    const int v  = deg[t];
    const int pd = (v + 7) & ~7;          // pad to multiple of 8
    lds[t] = pd;
    __syncthreads();
    for (int s = 1; s < 256; s <<= 1) {
        const int u = (t >= s) ? lds[t - s] : 0;
        __syncthreads();
        lds[t] += u;
        __syncthreads();
    }
    const int excl = r0 + lds[t] - pd;
    cur[t] = excl;
    if (n0 + t < N_NODES) { offS[n0 + t] = excl; offE[n0 + t] = excl + pd; }
    // dummy tail (disjoint from scatter range; no extra sync needed)
    for (int i = excl + v; i < excl + pd; ++i)
        srcD[i] = make_int2(N_NODES, 0);
    __syncthreads();
    for (int i = r0 + t; i < r1; i += 256) {
        const unsigned rc = rec[i];
        const int dl  = (int)(rc >> 16);
        const int src = (int)(rc & 0xFFFFu);
        const float dx = pos[src * 3]     - dpx[dl];
        const float dy = pos[src * 3 + 1] - dpy[dl];
        const float dz = pos[src * 3 + 2] - dpz[dl];
        const float d  = dx * dx + dy * dy + dz * dz;
        const int p = atomicAdd(&cur[dl], 1);
        srcD[p] = make_int2(src, __float_as_int(d));
    }
}

// ---------------------------------------------------------------------------
// Aggregate: ONE NODE PER WAVE, 4 groups x 16 lanes (8 ch/lane), 2-stage
// SOFTWARE PIPELINE: iteration i issues iteration i+1's Hsrc gathers (ids
// loaded two iterations ahead). Padded lists -> no masks/clamps on consume;
// issued-early gather index clamped to the dummy row (stale past-end ids).
// ---------------------------------------------------------------------------
__global__ __launch_bounds__(256) void aggr_kernel(
    const unsigned char* __restrict__ Hsrc8, const __bf16* __restrict__ Hdst,
    const float*  __restrict__ Wmsg,
    const int*    __restrict__ offS, const int*   __restrict__ offE,
    const int2*   __restrict__ srcD, __bf16* __restrict__ aggrB)
{
    const int lane = threadIdx.x & 63;
    const int wv   = threadIdx.x >> 6;
    const int g    = lane >> 4;          // edge sub-group 0..3
    const int c8   = (lane & 15) * 8;    // channel base (8 ch/lane)

    float w2[8], hd[8], acc[8];
    *(f32x4*)&w2[0] = *(const f32x4*)(Wmsg + 256 * C + c8);
    *(f32x4*)&w2[4] = *(const f32x4*)(Wmsg + 256 * C + c8 + 4);

    const int n = blockIdx.x * 4 + wv;   // 12500*4 == 50000 exactly
    const int o0 = offS[n], o1 = offE[n];
    {   // unpack Hdst row slice (bf16 -> f32)
        const u32x4 hdb = *(const u32x4*)(Hdst + (long)n * C + c8);
        #pragma unroll
        for (int k = 0; k < 4; ++k) {
            hd[2*k]   = __uint_as_float(hdb[k] << 16);
            hd[2*k+1] = __uint_as_float(hdb[k] & 0xffff0000u);
        }
    }
    #pragma unroll
    for (int j = 0; j < 8; ++j) acc[j] = 0.f;

    if (o1 > o0) {
        // pipeline fill: iter0 ids + gathers, iter1 ids
        int2 sdA0 = srcD[o0 + g];
        int2 sdA1 = srcD[o0 + 4 + g];
        uint2 huA0 = *(const uint2*)(Hsrc8 + (long)sdA0.x * C + c8);
        uint2 huA1 = *(const uint2*)(Hsrc8 + (long)sdA1.x * C + c8);
        int2 sdB0 = srcD[o0 + 8 + g];
        int2 sdB1 = srcD[o0 + 12 + g];
        for (int e = o0; e < o1; e += 8) {
            // issue NEXT iteration's gathers (clamped: past-end prefetch may
            // hold stale ids -> redirect to the inert dummy row)
            const long bx0 = (long)min((unsigned)sdB0.x, (unsigned)N_NODES);
            const long bx1 = (long)min((unsigned)sdB1.x, (unsigned)N_NODES);
            const uint2 huB0 = *(const uint2*)(Hsrc8 + bx0 * C + c8);
            const uint2 huB1 = *(const uint2*)(Hsrc8 + bx1 * C + c8);
            // load iter+2 ids (srcD has >=96B slack past the last region)
            const int2 sdC0 = srcD[e + 16 + g];
            const int2 sdC1 = srcD[e + 20 + g];
            const float d0 = __int_as_float(sdA0.y);
            const float d1 = __int_as_float(sdA1.y);

            {   // consume half 0: edge e+g
                const f32x2 p0 = __builtin_amdgcn_cvt_pk_f32_fp8((int)huA0.x, false);
                const f32x2 p1 = __builtin_amdgcn_cvt_pk_f32_fp8((int)huA0.x, true);
                const f32x2 p2 = __builtin_amdgcn_cvt_pk_f32_fp8((int)huA0.y, false);
                const f32x2 p3 = __builtin_amdgcn_cvt_pk_f32_fp8((int)huA0.y, true);
                const float hs[8] = {p0[0],p0[1],p1[0],p1[1],p2[0],p2[1],p3[0],p3[1]};
                #pragma unroll
                for (int j = 0; j < 8; ++j)
                    acc[j] += fmaxf(hs[j] + fmaf(d0, w2[j], hd[j]), 0.f);
            }
            {   // consume half 1: edge e+4+g
                const f32x2 p0 = __builtin_amdgcn_cvt_pk_f32_fp8((int)huA1.x, false);
                const f32x2 p1 = __builtin_amdgcn_cvt_pk_f32_fp8((int)huA1.x, true);
                const f32x2 p2 = __builtin_amdgcn_cvt_pk_f32_fp8((int)huA1.y, false);
                const f32x2 p3 = __builtin_amdgcn_cvt_pk_f32_fp8((int)huA1.y, true);
                const float hs[8] = {p0[0],p0[1],p1[0],p1[1],p2[0],p2[1],p3[0],p3[1]};
                #pragma unroll
                for (int j = 0; j < 8; ++j)
                    acc[j] += fmaxf(hs[j] + fmaf(d1, w2[j], hd[j]), 0.f);
            }
            // shift pipeline
            sdA0 = sdB0; sdA1 = sdB1; sdB0 = sdC0; sdB1 = sdC1;
            huA0 = huB0; huA1 = huB1;
        }
    }
    #pragma unroll
    for (int j = 0; j < 8; ++j) {        // combine the 4 edge groups
        acc[j] += __shfl_xor(acc[j], 16);
        acc[j] += __shfl_xor(acc[j], 32);
    }
    if (lane < 16) {
        bf16x8 v;
        #pragma unroll
        for (int j = 0; j < 8; ++j) v[j] = (__bf16)acc[j];
        *(bf16x8*)(aggrB + (long)n * C + c8) = v;
    }
}

// ---------------------------------------------------------------------------
// Node update: out = embed @ W_res + relu([embed, aggr] @ W_upd + b_upd)
// Reads pre-converted embedB (bf16) + aggrB (bf16). Grid 512 (~6 tiles/block
// amortizes the 96-value weight fragment load; halves L2 weight traffic).
// ---------------------------------------------------------------------------
__global__ __launch_bounds__(512) void node_upd_kernel(
    const __bf16* __restrict__ embedB, const __bf16* __restrict__ aggrB,
    const float* __restrict__ Wres,  const float* __restrict__ Wupd,
    const float* __restrict__ bupd,  float* __restrict__ out)
{
    __shared__ short ldsF[16 * 256];

    const int t = threadIdx.x, lane = t & 63, wave = t >> 6;
    const int chbase = wave * 16, q = lane >> 4, nr = lane & 15;

    bf16x8 aU[8], aR[4];
    {
        const int ch = chbase + nr;
        #pragma unroll
        for (int ks = 0; ks < 8; ++ks)
            #pragma unroll
            for (int i = 0; i < 8; ++i)
                aU[ks][i] = (__bf16)Wupd[(ks*32 + q*8 + i) * C + ch];
        #pragma unroll
        for (int ks = 0; ks < 4; ++ks)
            #pragma unroll
            for (int i = 0; i < 8; ++i)
                aR[ks][i] = (__bf16)Wres[(ks*32 + q*8 + i) * C + ch];
    }
    float bu[4];
    #pragma unroll
    for (int r = 0; r < 4; ++r) bu[r] = bupd[chbase + q*4 + r];

    for (int nt = blockIdx.x; nt < NTILES; nt += gridDim.x) {
        const int n0 = nt * 16;
        {   // stage [embedB | aggrB] (both bf16 copies) for 16 nodes
            const int nn = t >> 5, seg = t & 31;
            const __bf16* base = (seg < 16) ? embedB : aggrB;
            const bf16x8 v = *(const bf16x8*)(base + (long)(n0 + nn) * C + (seg & 15) * 8);
            *(bf16x8*)(&ldsF[swz8(nn, seg * 8)]) = v;
        }
        __syncthreads();

        f32x4 au = {0.f,0.f,0.f,0.f}, ar = {0.f,0.f,0.f,0.f};
        #pragma unroll
        for (int ks = 0; ks < 8; ++ks) {
            const bf16x8 b = *(const bf16x8*)(&ldsF[swz8(nr, ks * 32 + q * 8)]);
            au = __builtin_amdgcn_mfma_f32_16x16x32_bf16(aU[ks], b, au, 0, 0, 0);
        }
        #pragma unroll
        for (int ks = 0; ks < 4; ++ks) {
            const bf16x8 b = *(const bf16x8*)(&ldsF[swz8(nr, ks * 32 + q * 8)]);
            ar = __builtin_amdgcn_mfma_f32_16x16x32_bf16(aR[ks], b, ar, 0, 0, 0);
        }
        __syncthreads();

        const int node = n0 + nr;
        float* dst = out + (long)node * C + chbase + q * 4;
        #pragma unroll
        for (int r = 0; r < 4; ++r)
            dst[r] = ar[r] + fmaxf(au[r] + bu[r], 0.f);
    }
}

extern "C" void kernel_launch(void* const* d_in, const int* in_sizes, int n_in,
                              void* d_out, int out_size, void* d_ws, size_t ws_size,
                              hipStream_t stream) {
    const float* embed = (const float*)d_in[0];
    const float* pos   = (const float*)d_in[1];
    const float* Wres  = (const float*)d_in[2];
    const float* Wmsg  = (const float*)d_in[3];
    const float* bmsg  = (const float*)d_in[4];
    const float* Wupd  = (const float*)d_in[5];
    const float* bupd  = (const float*)d_in[6];
    const int*   eidx  = (const int*)d_in[7];
    float* out = (float*)d_out;

    char* ws = (char*)d_ws;
    int*            gcur  = (int*)(ws + WS_GCUR);
    int*            offS  = (int*)(ws + WS_OFFS);
    int*            offE  = (int*)(ws + WS_OFFE);
    int2*           srcD  = (int2*)(ws + WS_SRCD);
    unsigned*       rec   = (unsigned*)(ws + WS_REC);
    __bf16*         HdstB = (__bf16*)(ws + WS_HDST);
    unsigned char*  Hsrc8 = (unsigned char*)(ws + WS_HSRC8);
    __bf16*         embB  = (__bf16*)(ws + WS_EMBB);
    __bf16*         aggrB = (__bf16*)(ws + WS_AGGR);

    precomp_kernel<<<1024, 512, 0, stream>>>(embed, Wmsg, bmsg, Hsrc8, HdstB, embB, gcur);
    partition_kernel<<<N_EDGES / 1024, 256, 0, stream>>>(eidx, gcur, rec);
    bucket_csr_kernel<<<NB, 256, 0, stream>>>(rec, gcur, pos, offS, offE, srcD);
    aggr_kernel<<<N_NODES / 4, 256, 0, stream>>>(Hsrc8, HdstB, Wmsg, offS, offE, srcD, aggrB);
    node_upd_kernel<<<512, 512, 0, stream>>>(embB, aggrB, Wres, Wupd, bupd, out);
}